// Round 10
// baseline (256.754 us; speedup 1.0000x reference)
//
#include <hip/hip_runtime.h>
#include <hip/hip_bf16.h>
#include <math.h>

#define B_   2
#define N_   2048
#define D_   1024
#define H_   16
#define TD_  3072
#define LOG2E 1.44269504088896340736f
#define SCALE_Q (0.125f * LOG2E)

typedef short  bf16x8 __attribute__((ext_vector_type(8)));
typedef _Float16 f16x8 __attribute__((ext_vector_type(8)));
typedef _Float16 f16x4 __attribute__((ext_vector_type(4)));
typedef float  f32x4  __attribute__((ext_vector_type(4)));
typedef float  f32x16 __attribute__((ext_vector_type(16)));

#define MFMA32B(a, b, c)  __builtin_amdgcn_mfma_f32_32x32x16_bf16(a, b, c, 0, 0, 0)
#define MFMA32H(a, b, c)  __builtin_amdgcn_mfma_f32_32x32x16_f16(a, b, c, 0, 0, 0)

__device__ __forceinline__ ushort f2bf(float f) {
    union { float f; unsigned u; } v; v.f = f;
    unsigned r = (v.u + 0x7fffu + ((v.u >> 16) & 1u)) >> 16;
    return (ushort)r;
}
__device__ __forceinline__ unsigned pkrtz(float a, float b) {
    typedef __fp16 h2 __attribute__((ext_vector_type(2)));
    union { h2 h; unsigned u; } c;
    c.h = __builtin_amdgcn_cvt_pkrtz(a, b);
    return c.u;
}
__device__ __forceinline__ void async16(const void* g, void* l) {
    __builtin_amdgcn_global_load_lds(
        (const __attribute__((address_space(1))) unsigned*)g,
        (__attribute__((address_space(3))) unsigned*)l, 16, 0, 0);
}
// v_permlane32_swap_b32: out0 = {a.lanes[0:31], b.lanes[0:31]},
//                        out1 = {a.lanes[32:63], b.lanes[32:63]}
__device__ __forceinline__ void plswap(unsigned &a, unsigned &b) {
    auto r = __builtin_amdgcn_permlane32_swap((int)a, (int)b, false, false);
    a = (unsigned)r[0]; b = (unsigned)r[1];
}

// ---------------------------------------------------------------------------
// Preprocess: bf16 casts, mask->bitmask, log2-domain ppr bias row.
// ---------------------------------------------------------------------------
__global__ __launch_bounds__(256) void preprocess(
    const float* __restrict__ x, const float* __restrict__ W_in,
    const float* __restrict__ W_out, const float* __restrict__ ctx_ppr,
    const float* __restrict__ log_alpha, const int* __restrict__ n_ctx_p,
    const int* __restrict__ mask,
    ushort* __restrict__ xb, ushort* __restrict__ wib, ushort* __restrict__ wob,
    float* __restrict__ biasrow, unsigned* __restrict__ maskbits)
{
    const int J0 = 1048576, J1 = 786432, J2 = 262144, JM = 131072, JB = 2048;
    int t = blockIdx.x * 256 + threadIdx.x;
    if (t < J0 + J1 + J2) {
        const float* src; ushort* dst; int i = t;
        if (i < J0)           { src = x;      dst = xb;  }
        else if (i < J0 + J1) { i -= J0;      src = W_in;  dst = wib; }
        else                  { i -= J0 + J1; src = W_out; dst = wob; }
        float4 v = ((const float4*)src)[i];
        ushort4 o;
        o.x = f2bf(v.x); o.y = f2bf(v.y); o.z = f2bf(v.z); o.w = f2bf(v.w);
        ((ushort4*)dst)[i] = o;
    } else if (t < J0 + J1 + J2 + JM) {
        int i = t - (J0 + J1 + J2);
        const int4* m = (const int4*)(mask + (size_t)i * 32);
        unsigned bits = 0u;
        #pragma unroll
        for (int j = 0; j < 8; ++j) {
            int4 w = m[j];
            bits |= (w.x != 0 ? 1u : 0u) << (j * 4 + 0);
            bits |= (w.y != 0 ? 1u : 0u) << (j * 4 + 1);
            bits |= (w.z != 0 ? 1u : 0u) << (j * 4 + 2);
            bits |= (w.w != 0 ? 1u : 0u) << (j * 4 + 3);
        }
        maskbits[i] = bits;
    } else if (t < J0 + J1 + J2 + JM + JB) {
        int k = t - (J0 + J1 + J2 + JM);
        int nc = n_ctx_p[0];
        float bv = 0.f;
        if (k < nc) bv = log_alpha[0] * __log2f(fmaxf(ctx_ppr[k], 1e-8f));
        biasrow[k] = bv;   // log2-domain bias
    }
}

// ---------------------------------------------------------------------------
// bf16 NT GEMM, 128xBCOL tile, BK=64, 4 waves, 32x32x16 MFMA fragments.
// Counted-vmcnt double-buffer; XCD-chunked bijective block swizzle.
// MODE 0: f32 out (+bias), Ncol=1024.  MODE 1 (Ncol=3072): qkv epilogue —
// q*SCALE_Q->bf16 qk buffer, k->bf16 qk buffer, v*trust-gate->f16 V^T
// buffer [bh*64+dim][2048 tokens].
// ---------------------------------------------------------------------------
template<int BCOL, int MODE>
__global__ __launch_bounds__(256) void gemm32(
    const ushort* __restrict__ A, const ushort* __restrict__ Bw,
    const float* __restrict__ bias, float* __restrict__ Cout,
    ushort* __restrict__ qkout, _Float16* __restrict__ vTout,
    int Ncol, int K,
    const float* __restrict__ ctx_trust, const float* __restrict__ trust_scale,
    const int* __restrict__ n_ctx_p)
{
    constexpr int CT = BCOL / 64;        // col 32-tiles per wave
    constexpr int LB = BCOL / 32;        // B staging rounds (4KB each)
    constexpr int NCP = (MODE == 1 ? 3072 : 1024) / BCOL;  // col panels
    constexpr int NWG = NCP * 32;        // 32 row panels of 128
    constexpr int CHUNK = NWG / 8;
    __shared__ ushort tA[2][128 * 64];   // 2 x 16 KB
    __shared__ ushort tB[2][BCOL * 64];  // 2 x (BCOL/4) KB
    const int tid = threadIdx.x;
    const int lane = tid & 63, wv = tid >> 6;
    const int q31 = lane & 31, hi = lane >> 5;
    const int rh = wv >> 1, ch = wv & 1;
    // XCD-chunked bijective swizzle: CHUNK consecutive wg per XCD.
    const int id = blockIdx.x;
    const int wg = (id & 7) * CHUNK + (id >> 3);
    const int row0 = (wg / NCP) * 128, col0 = (wg % NCP) * BCOL;

    const int swz = q31 & 7;
    int offAr[2], offBr[CT];
    #pragma unroll
    for (int rt = 0; rt < 2; ++rt) offAr[rt] = (rh * 64 + rt * 32 + q31) * 64;
    #pragma unroll
    for (int ct = 0; ct < CT; ++ct) offBr[ct] = (ch * (BCOL / 2) + ct * 32 + q31) * 64;

    f32x16 acc[2][CT];
    #pragma unroll
    for (int i = 0; i < 2; ++i)
        #pragma unroll
        for (int j = 0; j < CT; ++j) acc[i][j] = (f32x16)(0.f);

    // staging constants: round r2 -> row g>>3 (128B = 8 granules of 16B),
    // source granule pre-swizzled by row&7; LDS dest linear (lane x 16B).
    int arow[4], asg[4], brow[LB], bsg[LB];
    #pragma unroll
    for (int r2 = 0; r2 < 4; ++r2) {
        int g = r2 * 256 + tid;
        arow[r2] = g >> 3; asg[r2] = ((g & 7) ^ ((g >> 3) & 7)) << 3;
    }
    #pragma unroll
    for (int r2 = 0; r2 < LB; ++r2) {
        int g = r2 * 256 + tid;
        brow[r2] = g >> 3; bsg[r2] = ((g & 7) ^ ((g >> 3) & 7)) << 3;
    }
    const ushort* Ab = A + (size_t)row0 * K;
    const ushort* Bb = Bw + (size_t)col0 * K;

    auto issue = [&](int ktile, int bufi) {
        const int kt = ktile * 64;
        #pragma unroll
        for (int r2 = 0; r2 < 4; ++r2)
            async16(Ab + (size_t)arow[r2] * K + kt + asg[r2],
                    &tA[bufi][(r2 * 256 + tid) * 8]);
        #pragma unroll
        for (int r2 = 0; r2 < LB; ++r2)
            async16(Bb + (size_t)brow[r2] * K + kt + bsg[r2],
                    &tB[bufi][(r2 * 256 + tid) * 8]);
    };

    issue(0, 0);
    const int NIT = K / 64;
    #pragma unroll 1
    for (int it = 0; it < NIT; ++it) {
        const int cur = it & 1;
        // bar1: all waves done with buf[cur^1] (computed last iter)
        asm volatile("s_barrier" ::: "memory");
        if (it + 1 < NIT) {
            issue(it + 1, cur ^ 1);
            // outstanding = L(tile it) + L(tile it+1); retire tile it only.
            // L = 4 + LB per tile.
            if constexpr (BCOL == 192)
                asm volatile("s_waitcnt vmcnt(10)" ::: "memory");
            else if constexpr (BCOL == 128)
                asm volatile("s_waitcnt vmcnt(8)" ::: "memory");
            else
                asm volatile("s_waitcnt vmcnt(6)" ::: "memory");
        } else {
            asm volatile("s_waitcnt vmcnt(0)" ::: "memory");
        }
        // bar2: every wave's tile-it loads have landed
        asm volatile("s_barrier" ::: "memory");

        const ushort* KA = tA[cur];
        const ushort* KB = tB[cur];
        __builtin_amdgcn_s_setprio(1);
        #pragma unroll
        for (int kk = 0; kk < 4; ++kk) {
            const int gr = ((kk * 2 + hi) ^ swz) << 3;
            bf16x8 af[2], bfv[CT];
            #pragma unroll
            for (int rt = 0; rt < 2; ++rt)
                af[rt] = *(const bf16x8*)&KA[offAr[rt] + gr];
            #pragma unroll
            for (int ct = 0; ct < CT; ++ct)
                bfv[ct] = *(const bf16x8*)&KB[offBr[ct] + gr];
            #pragma unroll
            for (int rt = 0; rt < 2; ++rt)
                #pragma unroll
                for (int ct = 0; ct < CT; ++ct)
                    acc[rt][ct] = MFMA32B(af[rt], bfv[ct], acc[rt][ct]);
        }
        __builtin_amdgcn_s_setprio(0);
    }

    // ---- epilogue: 32x32 C layout: col = cbase + (lane&31),
    //      row = rbase + (reg&3) + 8*(reg>>2) + 4*(lane>>5) ----
    const int nctx = n_ctx_p ? n_ctx_p[0] : 0;
    const float ts = trust_scale ? trust_scale[0] : 0.f;
    #pragma unroll
    for (int ct = 0; ct < CT; ++ct) {
        const int col = col0 + ch * (BCOL / 2) + ct * 32 + q31;
        const float bv = bias[col];
        #pragma unroll
        for (int rt = 0; rt < 2; ++rt) {
            const int rb0 = row0 + rh * 64 + rt * 32 + 4 * hi;
            f32x16 a = acc[rt][ct];
            if (MODE == 0) {
                #pragma unroll
                for (int g2 = 0; g2 < 4; ++g2)
                    #pragma unroll
                    for (int r = 0; r < 4; ++r)
                        Cout[(size_t)(rb0 + 8 * g2 + r) * Ncol + col] = a[g2 * 4 + r] + bv;
            } else if (col < D_) {
                #pragma unroll
                for (int g2 = 0; g2 < 4; ++g2)
                    #pragma unroll
                    for (int r = 0; r < 4; ++r)
                        qkout[(size_t)(rb0 + 8 * g2 + r) * 2048 + col] =
                            f2bf((a[g2 * 4 + r] + bv) * SCALE_Q);
            } else if (col < 2 * D_) {
                #pragma unroll
                for (int g2 = 0; g2 < 4; ++g2)
                    #pragma unroll
                    for (int r = 0; r < 4; ++r)
                        qkout[(size_t)(rb0 + 8 * g2 + r) * 2048 + col] =
                            f2bf(a[g2 * 4 + r] + bv);
            } else {
                const int vc = col - 2 * D_;
                const int hh = vc >> 6, dim = vc & 63;
                const int bb = row0 >> 11;
                #pragma unroll
                for (int g2 = 0; g2 < 4; ++g2) {
                    const int nbase = (rb0 + 8 * g2) & (N_ - 1);
                    ushort4 o;
                    #pragma unroll
                    for (int r = 0; r < 4; ++r) {
                        float v = a[g2 * 4 + r] + bv;
                        const int n = nbase + r;
                        if (n < nctx)
                            v *= 1.f / (1.f + __expf(-ts * ctx_trust[n]));
                        _Float16 hv = (_Float16)v;
                        ((ushort*)&o)[r] = *(ushort*)&hv;
                    }
                    *(ushort4*)&vTout[((size_t)(bb * 16 + hh) * 64 + dim) * 2048 + nbase] = o;
                }
            }
        }
    }
}

// ---------------------------------------------------------------------------
// Flash attention, 32x32 MFMA, max-less log2-domain softmax.
// Split-K 2-way (blockIdx.z = key half, now 8 chunks of 128 keys each).
// 128-key chunks halve barrier pairs (16->8) and staging-address VALU;
// K dbuf [2][128x64], V dbuf [2][64 dims][128 keys] = 64 KB LDS, 2 blk/CU.
// FIFO per iter: mask(uint4) + 4 K + 4 V = 9 issues; steady vmcnt(9).
// __launch_bounds__(256,2): 256-VGPR budget keeps S/softmax state in arch
// VGPRs (no accvgpr round-trips, the R2 regression source).
// ---------------------------------------------------------------------------
__global__ __launch_bounds__(256, 2) void attn(
    const ushort* __restrict__ qkb,      // [4096][2048] bf16: q | k
    const _Float16* __restrict__ vT,     // [32*64][2048] f16  (b,h,dim) x token
    const unsigned* __restrict__ maskbits,
    const float* __restrict__ biasrow,   // log2-domain, 0 beyond n_ctx
    const int* __restrict__ n_ctx_p,
    _Float16* __restrict__ op0,          // [4096][1024] f16 partial, key-half 0
    _Float16* __restrict__ op1,          // [4096][1024] f16 partial, key-half 1
    float* __restrict__ lpart)           // [2][32*2048] denominators
{
    __shared__ ushort   Kt[2][128 * 64]; // 32 KB  [key][dim]
    __shared__ _Float16 Vt[2][64 * 128]; // 32 KB  [dim][key]
    const int tid = threadIdx.x;
    const int lane = tid & 63, wv = tid >> 6;
    const int q31 = lane & 31, hi = lane >> 5;
    const int b = blockIdx.y >> 4, h = blockIdx.y & 15;
    const int q0w = blockIdx.x * 128 + wv * 32;
    const int kh = blockIdx.z;           // key half: 0 or 1
    const int kbase = kh << 10;
    const int nctx = n_ctx_p[0];

    // chunk-order rotation: co-resident blocks de-convoy their phases
    const int lin = blockIdx.x + (blockIdx.y << 4) + (blockIdx.z << 9);
    const int rot = ((lin >> 8) << 1) & 7;

    union fi { float f; int i; };
    fi ng; ng.f = -1e30f;
    const int NEGI = ng.i;

    // Q B-fragments: B[k=dim][n=q], lane n=q31, k = hi*8+j per kstep
    bf16x8 qf[4];
    {
        const ushort* qrow = qkb + (size_t)(b * N_ + q0w + q31) * 2048 + h * 64;
        #pragma unroll
        for (int ks = 0; ks < 4; ++ks)
            qf[ks] = *(const bf16x8*)(qrow + ks * 16 + hi * 8);
    }
    const size_t kgbase = (size_t)(b * N_ + kbase) * 2048 + 1024 + h * 64;
    const _Float16* vbase = vT + (size_t)((b * 16 + h) * 64) * 2048 + kbase;
    const unsigned* mrow = maskbits + (size_t)(q0w + q31) * 64 + (kbase >> 5);

    // staging offsets (per 128-key chunk):
    // K tile [128 keys][64 dims]: granule g: row=g>>3, sg=(g&7)^(row&7)
    // V tile [64 dims][128 keys]: granule g: row=g>>4, sg=(g&15)^(row&7)
    int goffK[4], goffV[4], ldso[4];
    #pragma unroll
    for (int r2 = 0; r2 < 4; ++r2) {
        int g = r2 * 256 + tid;
        int rK = g >> 3, sK = (g & 7) ^ (rK & 7);
        goffK[r2] = rK * 2048 + sK * 8;
        int rV = g >> 4, sV = (g & 15) ^ (rV & 7);
        goffV[r2] = rV * 2048 + sV * 8;
        ldso[r2] = g * 8;
    }

    f32x16 O[2];
    O[0] = (f32x16)(0.f); O[1] = (f32x16)(0.f);
    float lrun = 0.f;

    // ---- prologue: FIFO = [mask0][K0 x4][V0 x4] ----
    const int cp0 = rot;
    uint4 mcur = *(const uint4*)&mrow[cp0 * 4];
    asm volatile("" ::: "memory");       // pin mask load before the asyncs
    {
        const ushort* gp = qkb + kgbase + (size_t)cp0 * (128 * 2048);
        #pragma unroll
        for (int r2 = 0; r2 < 4; ++r2) async16(gp + goffK[r2], &Kt[0][ldso[r2]]);
        const _Float16* vp = vbase + cp0 * 128;
        #pragma unroll
        for (int r2 = 0; r2 < 4; ++r2) async16(vp + goffV[r2], &Vt[0][ldso[r2]]);
    }

    const int swz = q31 & 7;
    #pragma unroll 1
    for (int ci = 0; ci < 8; ++ci) {
        // bar1: all waves done computing chunk ci-1 -> buffer reusable
        asm volatile("s_barrier" ::: "memory");
        uint4 mnext = mcur;
        if (ci < 7) {
            const int cpn = (ci + 1 + rot) & 7;
            mnext = *(const uint4*)&mrow[cpn * 4];
            asm volatile("" ::: "memory");   // pin mask before asyncs
            const ushort* gp = qkb + kgbase + (size_t)cpn * (128 * 2048);
            #pragma unroll
            for (int r2 = 0; r2 < 4; ++r2)
                async16(gp + goffK[r2], &Kt[(ci + 1) & 1][ldso[r2]]);
            const _Float16* vp = vbase + cpn * 128;
            #pragma unroll
            for (int r2 = 0; r2 < 4; ++r2)
                async16(vp + goffV[r2], &Vt[(ci + 1) & 1][ldso[r2]]);
            // steady FIFO: [mask ci][K ci x4][V ci x4][mask ci+1][K/V ci+1 x8]
            // retire through V(ci); keep the 9 newest in flight.
            asm volatile("s_waitcnt vmcnt(9)" ::: "memory");
        } else {
            asm volatile("s_waitcnt vmcnt(0)" ::: "memory");
        }
        // bar2: all waves' chunk-ci loads have landed
        asm volatile("s_barrier" ::: "memory");

        const ushort*   KT = Kt[ci & 1];
        const _Float16* VT = Vt[ci & 1];
        const int cp = (ci + rot) & 7;
        const int c0g = kbase + cp * 128;
        const bool has_bias = (c0g < nctx);
        const unsigned mw[4] = { mcur.x, mcur.y, mcur.z, mcur.w };
        float lsum = 0.f;

        #pragma unroll
        for (int t = 0; t < 4; ++t) {
            // ---- S^T tile = K . Q^T (32 keys) ----
            f32x16 S = (f32x16)(0.f);
            const int rbase = (t * 32 + q31) * 64;
            __builtin_amdgcn_s_setprio(1);
            #pragma unroll
            for (int ks = 0; ks < 4; ++ks) {
                bf16x8 kf = *(const bf16x8*)&KT[rbase + (((ks * 2 + hi) ^ swz) << 3)];
                S = MFMA32B(kf, qf[ks], S);
            }
            __builtin_amdgcn_s_setprio(0);

            // ---- softmax (no max, no offset; mask via bfe+bfi) ----
            const unsigned msh = mw[t] >> (hi * 4);
            unsigned pk[8];
            float lt = 0.f;
            #pragma unroll
            for (int g = 0; g < 4; ++g) {
                f32x4 bb;
                if (has_bias)
                    bb = *(const f32x4*)&biasrow[c0g + t * 32 + g * 8 + hi * 4];
                float pr[4];
                #pragma unroll
                for (int r = 0; r < 4; ++r) {
                    const int br = r + 8 * g;      // bit pos after >> 4*hi
                    float s = S[g * 4 + r];
                    if (has_bias) s += bb[r];
                    int mi = ((int)(msh << (31 - br))) >> 31;  // v_bfe_i32
                    fi su; su.f = s;
                    su.i = (mi & NEGI) | (su.i & ~mi);         // v_bfi_b32
                    pr[r] = __builtin_amdgcn_exp2f(su.f);
                }
                lt += (pr[0] + pr[1]) + (pr[2] + pr[3]);
                pk[g * 2 + 0] = pkrtz(pr[0], pr[1]);
                pk[g * 2 + 1] = pkrtz(pr[2], pr[3]);
            }
            lsum += lt;

            // ---- PV for this tile: out^T += V^T . P^T ----
            __builtin_amdgcn_s_setprio(1);
            #pragma unroll
            for (int kss = 0; kss < 2; ++kss) {
                const int lo4 = kss * 4;
                unsigned w0 = pk[lo4 + 0], w1 = pk[lo4 + 1];
                unsigned w2 = pk[lo4 + 2], w3 = pk[lo4 + 3];
                plswap(w0, w2);
                plswap(w1, w3);
                union { f16x8 v; unsigned u[4]; } frag;
                frag.u[0] = w0; frag.u[1] = w1;
                frag.u[2] = w2; frag.u[3] = w3;
                // V slot: key-granule (t*4 + kss*2 + hi) of 16 per dim-row
                const int vslot = ((t * 4 + kss * 2 + hi) ^ swz) << 3;
                #pragma unroll
                for (int t2 = 0; t2 < 2; ++t2) {
                    const int vb = (t2 * 32 + q31) * 128;
                    union { f16x8 v; int4 i4; } vf;
                    vf.i4 = *(const int4*)&VT[vb + vslot];
                    O[t2] = MFMA32H(vf.v, frag.v, O[t2]);
                }
            }
            __builtin_amdgcn_s_setprio(0);
        }
        lrun += lsum;
        mcur = mnext;
    }

    // ---- epilogue: normalize this half, store f16 partial + denominator ----
    float l = lrun + __shfl_xor(lrun, 32);
    float inv = 1.f / l;
    _Float16* orow = (kh ? op1 : op0)
                   + (size_t)(b * N_ + q0w + q31) * 1024 + h * 64;
    #pragma unroll
    for (int t = 0; t < 2; ++t)
        #pragma unroll
        for (int g = 0; g < 4; ++g) {
            ushort4 o;
            #pragma unroll
            for (int r = 0; r < 4; ++r) {
                _Float16 hv = (_Float16)(O[t][g * 4 + r] * inv);  // RTN cvt
                ((ushort*)&o)[r] = *(ushort*)&hv;
            }
            *(ushort4*)&orow[t * 32 + g * 8 + hi * 4] = o;
        }
    if (hi == 0)
        lpart[(kh << 16) + (b * 16 + h) * 2048 + q0w + q31] = l;
}

// ---------------------------------------------------------------------------
// Combine the two key-half partials: out = (o0*l0 + o1*l1) / (l0+l1), bf16.
// attb may alias op1: each thread reads exactly the bytes it overwrites.
// ---------------------------------------------------------------------------
__global__ __launch_bounds__(256) void combine(
    const _Float16* __restrict__ op0, const _Float16* __restrict__ op1,
    const float* __restrict__ lpart, ushort* __restrict__ attb)
{
    int t = blockIdx.x * 256 + threadIdx.x;
    size_t idx = (size_t)t * 4;
    int col = (int)(idx & 1023);          // h*64 + d
    int row = (int)(idx >> 10);           // b*2048 + q
    int h = col >> 6;
    int b = row >> 11, q = row & 2047;
    int lidx = (b * 16 + h) * 2048 + q;
    float l0 = lpart[lidx], l1 = lpart[65536 + lidx];
    float inv = 1.f / (l0 + l1);
    float w0 = l0 * inv, w1 = l1 * inv;
    f16x4 a0 = *(const f16x4*)(op0 + idx);
    f16x4 a1 = *(const f16x4*)(op1 + idx);
    ushort4 o;
    #pragma unroll
    for (int r = 0; r < 4; ++r)
        ((ushort*)&o)[r] = f2bf((float)a0[r] * w0 + (float)a1[r] * w1);
    *(ushort4*)(attb + idx) = o;
}

extern "C" void kernel_launch(void* const* d_in, const int* in_sizes, int n_in,
                              void* d_out, int out_size, void* d_ws, size_t ws_size,
                              hipStream_t stream)
{
    const float* x         = (const float*)d_in[0];
    const float* ctx_ppr   = (const float*)d_in[1];
    const float* ctx_trust = (const float*)d_in[2];
    const int*   n_ctx_p   = (const int*)d_in[3];
    const int*   attn_mask = (const int*)d_in[4];
    const float* W_in      = (const float*)d_in[5];
    const float* b_in      = (const float*)d_in[6];
    const float* W_out     = (const float*)d_in[7];
    const float* b_out     = (const float*)d_in[8];
    const float* log_alpha = (const float*)d_in[9];
    const float* trust_sc  = (const float*)d_in[10];
    float* out = (float*)d_out;

    char* ws = (char*)d_ws;
    ushort*    xb       = (ushort*)ws;    ws += (size_t)4096 * 1024 * 2;   // 8 MB
    ushort*    wib      = (ushort*)ws;    ws += (size_t)3072 * 1024 * 2;   // 6 MB
    ushort*    wob      = (ushort*)ws;    ws += (size_t)1024 * 1024 * 2;   // 2 MB
    ushort*    qkb      = (ushort*)ws;    ws += (size_t)4096 * 2048 * 2;   // 16 MB
    _Float16*  vT       = (_Float16*)ws;  ws += (size_t)2048 * 2048 * 2;   // 8 MB
    ushort*    attbuf   = (ushort*)ws;    ws += (size_t)4096 * 1024 * 2;   // 8 MB
    float*     biasrow  = (float*)ws;     ws += 2048 * 4;
    unsigned*  maskbits = (unsigned*)ws;  ws += (size_t)2048 * 64 * 4;     // 512 KB

    // Split-K partials live in workspace that is dead once the QKV GEMM ran:
    //   op0   aliases xb   (8 MB, exact fit)
    //   lpart aliases wib  (512 KB into 6 MB)
    //   op1   aliases attbuf (combine reads op1[i] then writes attb[i]:
    //                         byte-identical per thread, sequential stream)
    _Float16* op0   = (_Float16*)xb;
    _Float16* op1   = (_Float16*)attbuf;
    float*    lpart = (float*)wib;

    hipLaunchKernelGGL(preprocess, dim3(8712), dim3(256), 0, stream,
                       x, W_in, W_out, ctx_ppr, log_alpha, n_ctx_p, attn_mask,
                       xb, wib, wob, biasrow, maskbits);

    hipLaunchKernelGGL((gemm32<192, 1>), dim3(512), dim3(256), 0, stream,
                       xb, wib, b_in, (float*)nullptr, qkb, vT, TD_, 1024,
                       ctx_trust, trust_sc, n_ctx_p);

    hipLaunchKernelGGL(attn, dim3(16, 32, 2), dim3(256), 0, stream,
                       qkb, vT, maskbits, biasrow, n_ctx_p, op0, op1, lpart);

    hipLaunchKernelGGL(combine, dim3(4096), dim3(256), 0, stream,
                       op0, op1, lpart, attbuf);

    hipLaunchKernelGGL((gemm32<64, 0>), dim3(512), dim3(256), 0, stream,
                       attbuf, wob, b_out, out, (ushort*)nullptr, (_Float16*)nullptr,
                       1024, 1024, ctx_trust, trust_sc, n_ctx_p);
}

// Round 11
// 242.755 us; speedup vs baseline: 1.0577x; 1.0577x over previous
//
#include <hip/hip_runtime.h>
#include <hip/hip_bf16.h>
#include <math.h>

#define B_   2
#define N_   2048
#define D_   1024
#define H_   16
#define TD_  3072
#define LOG2E 1.44269504088896340736f
#define SCALE_Q (0.125f * LOG2E)

typedef short  bf16x8 __attribute__((ext_vector_type(8)));
typedef _Float16 f16x8 __attribute__((ext_vector_type(8)));
typedef _Float16 f16x4 __attribute__((ext_vector_type(4)));
typedef float  f32x4  __attribute__((ext_vector_type(4)));
typedef float  f32x16 __attribute__((ext_vector_type(16)));

#define MFMA32B(a, b, c)  __builtin_amdgcn_mfma_f32_32x32x16_bf16(a, b, c, 0, 0, 0)
#define MFMA32H(a, b, c)  __builtin_amdgcn_mfma_f32_32x32x16_f16(a, b, c, 0, 0, 0)

__device__ __forceinline__ ushort f2bf(float f) {
    union { float f; unsigned u; } v; v.f = f;
    unsigned r = (v.u + 0x7fffu + ((v.u >> 16) & 1u)) >> 16;
    return (ushort)r;
}
__device__ __forceinline__ unsigned pkrtz(float a, float b) {
    typedef __fp16 h2 __attribute__((ext_vector_type(2)));
    union { h2 h; unsigned u; } c;
    c.h = __builtin_amdgcn_cvt_pkrtz(a, b);
    return c.u;
}
__device__ __forceinline__ void async16(const void* g, void* l) {
    __builtin_amdgcn_global_load_lds(
        (const __attribute__((address_space(1))) unsigned*)g,
        (__attribute__((address_space(3))) unsigned*)l, 16, 0, 0);
}
// v_permlane32_swap_b32: out0 = {a.lanes[0:31], b.lanes[0:31]},
//                        out1 = {a.lanes[32:63], b.lanes[32:63]}
__device__ __forceinline__ void plswap(unsigned &a, unsigned &b) {
    auto r = __builtin_amdgcn_permlane32_swap((int)a, (int)b, false, false);
    a = (unsigned)r[0]; b = (unsigned)r[1];
}

// ---------------------------------------------------------------------------
// Preprocess: bf16 casts, mask->bitmask, log2-domain ppr bias row.
// ---------------------------------------------------------------------------
__global__ __launch_bounds__(256) void preprocess(
    const float* __restrict__ x, const float* __restrict__ W_in,
    const float* __restrict__ W_out, const float* __restrict__ ctx_ppr,
    const float* __restrict__ log_alpha, const int* __restrict__ n_ctx_p,
    const int* __restrict__ mask,
    ushort* __restrict__ xb, ushort* __restrict__ wib, ushort* __restrict__ wob,
    float* __restrict__ biasrow, unsigned* __restrict__ maskbits)
{
    const int J0 = 1048576, J1 = 786432, J2 = 262144, JM = 131072, JB = 2048;
    int t = blockIdx.x * 256 + threadIdx.x;
    if (t < J0 + J1 + J2) {
        const float* src; ushort* dst; int i = t;
        if (i < J0)           { src = x;      dst = xb;  }
        else if (i < J0 + J1) { i -= J0;      src = W_in;  dst = wib; }
        else                  { i -= J0 + J1; src = W_out; dst = wob; }
        float4 v = ((const float4*)src)[i];
        ushort4 o;
        o.x = f2bf(v.x); o.y = f2bf(v.y); o.z = f2bf(v.z); o.w = f2bf(v.w);
        ((ushort4*)dst)[i] = o;
    } else if (t < J0 + J1 + J2 + JM) {
        int i = t - (J0 + J1 + J2);
        const int4* m = (const int4*)(mask + (size_t)i * 32);
        unsigned bits = 0u;
        #pragma unroll
        for (int j = 0; j < 8; ++j) {
            int4 w = m[j];
            bits |= (w.x != 0 ? 1u : 0u) << (j * 4 + 0);
            bits |= (w.y != 0 ? 1u : 0u) << (j * 4 + 1);
            bits |= (w.z != 0 ? 1u : 0u) << (j * 4 + 2);
            bits |= (w.w != 0 ? 1u : 0u) << (j * 4 + 3);
        }
        maskbits[i] = bits;
    } else if (t < J0 + J1 + J2 + JM + JB) {
        int k = t - (J0 + J1 + J2 + JM);
        int nc = n_ctx_p[0];
        float bv = 0.f;
        if (k < nc) bv = log_alpha[0] * __log2f(fmaxf(ctx_ppr[k], 1e-8f));
        biasrow[k] = bv;   // log2-domain bias
    }
}

// ---------------------------------------------------------------------------
// bf16 NT GEMM, 128xBCOL tile, BK=64, 4 waves, 32x32x16 MFMA fragments.
// Counted-vmcnt double-buffer; XCD-chunked bijective block swizzle.
// MODE 0: f32 out (+bias), Ncol=1024.  MODE 1 (Ncol=3072): qkv epilogue —
// q*SCALE_Q->bf16 qk buffer, k->bf16 qk buffer, v*trust-gate->f16 V^T.
// NEW: the V^T store goes through a per-wave LDS transpose (tB[0] is dead
// in the last K-iteration, cur=1) so global stores are 64B-coalesced
// token-runs instead of 8B scatters at 4KB stride (64 lines/instr -> 8).
// Values are bit-identical to the old path; only store order changes.
// ---------------------------------------------------------------------------
template<int BCOL, int MODE>
__global__ __launch_bounds__(256) void gemm32(
    const ushort* __restrict__ A, const ushort* __restrict__ Bw,
    const float* __restrict__ bias, float* __restrict__ Cout,
    ushort* __restrict__ qkout, _Float16* __restrict__ vTout,
    int Ncol, int K,
    const float* __restrict__ ctx_trust, const float* __restrict__ trust_scale,
    const int* __restrict__ n_ctx_p)
{
    constexpr int CT = BCOL / 64;        // col 32-tiles per wave
    constexpr int LB = BCOL / 32;        // B staging rounds (4KB each)
    constexpr int NCP = (MODE == 1 ? 3072 : 1024) / BCOL;  // col panels
    constexpr int NWG = NCP * 32;        // 32 row panels of 128
    constexpr int CHUNK = NWG / 8;
    __shared__ ushort tA[2][128 * 64];   // 2 x 16 KB
    __shared__ ushort tB[2][BCOL * 64];  // 2 x (BCOL/4) KB
    const int tid = threadIdx.x;
    const int lane = tid & 63, wv = tid >> 6;
    const int q31 = lane & 31, hi = lane >> 5;
    const int rh = wv >> 1, ch = wv & 1;
    // XCD-chunked bijective swizzle: CHUNK consecutive wg per XCD.
    const int id = blockIdx.x;
    const int wg = (id & 7) * CHUNK + (id >> 3);
    const int row0 = (wg / NCP) * 128, col0 = (wg % NCP) * BCOL;

    const int swz = q31 & 7;
    int offAr[2], offBr[CT];
    #pragma unroll
    for (int rt = 0; rt < 2; ++rt) offAr[rt] = (rh * 64 + rt * 32 + q31) * 64;
    #pragma unroll
    for (int ct = 0; ct < CT; ++ct) offBr[ct] = (ch * (BCOL / 2) + ct * 32 + q31) * 64;

    f32x16 acc[2][CT];
    #pragma unroll
    for (int i = 0; i < 2; ++i)
        #pragma unroll
        for (int j = 0; j < CT; ++j) acc[i][j] = (f32x16)(0.f);

    // staging constants: round r2 -> row g>>3 (128B = 8 granules of 16B),
    // source granule pre-swizzled by row&7; LDS dest linear (lane x 16B).
    int arow[4], asg[4], brow[LB], bsg[LB];
    #pragma unroll
    for (int r2 = 0; r2 < 4; ++r2) {
        int g = r2 * 256 + tid;
        arow[r2] = g >> 3; asg[r2] = ((g & 7) ^ ((g >> 3) & 7)) << 3;
    }
    #pragma unroll
    for (int r2 = 0; r2 < LB; ++r2) {
        int g = r2 * 256 + tid;
        brow[r2] = g >> 3; bsg[r2] = ((g & 7) ^ ((g >> 3) & 7)) << 3;
    }
    const ushort* Ab = A + (size_t)row0 * K;
    const ushort* Bb = Bw + (size_t)col0 * K;

    auto issue = [&](int ktile, int bufi) {
        const int kt = ktile * 64;
        #pragma unroll
        for (int r2 = 0; r2 < 4; ++r2)
            async16(Ab + (size_t)arow[r2] * K + kt + asg[r2],
                    &tA[bufi][(r2 * 256 + tid) * 8]);
        #pragma unroll
        for (int r2 = 0; r2 < LB; ++r2)
            async16(Bb + (size_t)brow[r2] * K + kt + bsg[r2],
                    &tB[bufi][(r2 * 256 + tid) * 8]);
    };

    issue(0, 0);
    const int NIT = K / 64;
    #pragma unroll 1
    for (int it = 0; it < NIT; ++it) {
        const int cur = it & 1;
        // bar1: all waves done with buf[cur^1] (computed last iter)
        asm volatile("s_barrier" ::: "memory");
        if (it + 1 < NIT) {
            issue(it + 1, cur ^ 1);
            // outstanding = L(tile it) + L(tile it+1); retire tile it only.
            // L = 4 + LB per tile.
            if constexpr (BCOL == 192)
                asm volatile("s_waitcnt vmcnt(10)" ::: "memory");
            else if constexpr (BCOL == 128)
                asm volatile("s_waitcnt vmcnt(8)" ::: "memory");
            else
                asm volatile("s_waitcnt vmcnt(6)" ::: "memory");
        } else {
            asm volatile("s_waitcnt vmcnt(0)" ::: "memory");
        }
        // bar2: every wave's tile-it loads have landed
        asm volatile("s_barrier" ::: "memory");

        const ushort* KA = tA[cur];
        const ushort* KB = tB[cur];
        __builtin_amdgcn_s_setprio(1);
        #pragma unroll
        for (int kk = 0; kk < 4; ++kk) {
            const int gr = ((kk * 2 + hi) ^ swz) << 3;
            bf16x8 af[2], bfv[CT];
            #pragma unroll
            for (int rt = 0; rt < 2; ++rt)
                af[rt] = *(const bf16x8*)&KA[offAr[rt] + gr];
            #pragma unroll
            for (int ct = 0; ct < CT; ++ct)
                bfv[ct] = *(const bf16x8*)&KB[offBr[ct] + gr];
            #pragma unroll
            for (int rt = 0; rt < 2; ++rt)
                #pragma unroll
                for (int ct = 0; ct < CT; ++ct)
                    acc[rt][ct] = MFMA32B(af[rt], bfv[ct], acc[rt][ct]);
        }
        __builtin_amdgcn_s_setprio(0);
    }
    // After it=NIT-1 (cur=1): all waves past bar2, only tA[1]/tB[1] are read.
    // tB[0] (>=8KB) is dead -> per-wave transpose scratch, no extra barrier.
    ushort* vscr = &tB[0][0];

    // ---- epilogue: 32x32 C layout: col = cbase + (lane&31),
    //      row = rbase + (reg&3) + 8*(reg>>2) + 4*(lane>>5) ----
    const int nctx = n_ctx_p ? n_ctx_p[0] : 0;
    const float ts = trust_scale ? trust_scale[0] : 0.f;
    #pragma unroll
    for (int ct = 0; ct < CT; ++ct) {
        const int col = col0 + ch * (BCOL / 2) + ct * 32 + q31;
        const float bv = bias[col];
        #pragma unroll
        for (int rt = 0; rt < 2; ++rt) {
            const int rb0 = row0 + rh * 64 + rt * 32 + 4 * hi;
            f32x16 a = acc[rt][ct];
            if (MODE == 0) {
                #pragma unroll
                for (int g2 = 0; g2 < 4; ++g2)
                    #pragma unroll
                    for (int r = 0; r < 4; ++r)
                        Cout[(size_t)(rb0 + 8 * g2 + r) * Ncol + col] = a[g2 * 4 + r] + bv;
            } else if (col < D_) {
                #pragma unroll
                for (int g2 = 0; g2 < 4; ++g2)
                    #pragma unroll
                    for (int r = 0; r < 4; ++r)
                        qkout[(size_t)(rb0 + 8 * g2 + r) * 2048 + col] =
                            f2bf((a[g2 * 4 + r] + bv) * SCALE_Q);
            } else if (col < 2 * D_) {
                #pragma unroll
                for (int g2 = 0; g2 < 4; ++g2)
                    #pragma unroll
                    for (int r = 0; r < 4; ++r)
                        qkout[(size_t)(rb0 + 8 * g2 + r) * 2048 + col] =
                            f2bf(a[g2 * 4 + r] + bv);
            } else {
                // ---- V tile (32 tokens x 32 dims): LDS transpose ----
                const int vc0 = col0 + ch * (BCOL / 2) + ct * 32 - 2 * D_;
                const int hh = vc0 >> 6;
                const int dim0 = vc0 & 63;            // 0 or 32
                const int bb = row0 >> 11;
                const int tok0 = (row0 + rh * 64 + rt * 32) & (N_ - 1);
                ushort* scr = vscr + wv * 2560;       // [32 dims][36] padded
                // lane = dim q31: write its 16 tokens (4 per g2), transposed
                #pragma unroll
                for (int g2 = 0; g2 < 4; ++g2) {
                    ushort4 o;
                    #pragma unroll
                    for (int r = 0; r < 4; ++r) {
                        float v = a[g2 * 4 + r] + bv;
                        const int n = tok0 + 4 * hi + 8 * g2 + r;
                        if (n < nctx)
                            v *= 1.f / (1.f + __expf(-ts * ctx_trust[n]));
                        _Float16 hv = (_Float16)v;
                        ((ushort*)&o)[r] = *(ushort*)&hv;
                    }
                    *(ushort4*)&scr[q31 * 36 + 4 * hi + 8 * g2] = o;
                }
                asm volatile("s_waitcnt lgkmcnt(0)" ::: "memory");
                __builtin_amdgcn_sched_barrier(0);
                // read dim-rows, store 64B-coalesced token runs:
                // iter i: dims i*8+(lane>>3), tokens (lane&7)*4..+3
                #pragma unroll
                for (int i = 0; i < 4; ++i) {
                    const int d = i * 8 + (lane >> 3);
                    const int t0 = (lane & 7) * 4;
                    ushort4 o = *(ushort4*)&scr[d * 36 + t0];
                    *(ushort4*)&vTout[((size_t)(bb * 16 + hh) * 64 + dim0 + d)
                                      * 2048 + tok0 + t0] = o;
                }
                asm volatile("s_waitcnt lgkmcnt(0)" ::: "memory");
                __builtin_amdgcn_sched_barrier(0);    // scr reusable next tile
            }
        }
    }
}

// ---------------------------------------------------------------------------
// Flash attention, 32x32 MFMA, max-less log2-domain softmax.
// Reverted to the Round-9 64-key version (69.4-70.0 us measured; the
// 128-key variant regressed to 77.9 via occupancy loss).
// ---------------------------------------------------------------------------
__global__ __launch_bounds__(256, 4) void attn(
    const ushort* __restrict__ qkb,      // [4096][2048] bf16: q | k
    const _Float16* __restrict__ vT,     // [32*64][2048] f16  (b,h,dim) x token
    const unsigned* __restrict__ maskbits,
    const float* __restrict__ biasrow,   // log2-domain, 0 beyond n_ctx
    const int* __restrict__ n_ctx_p,
    _Float16* __restrict__ op0,          // [4096][1024] f16 partial, key-half 0
    _Float16* __restrict__ op1,          // [4096][1024] f16 partial, key-half 1
    float* __restrict__ lpart)           // [2][32*2048] denominators
{
    __shared__ ushort   Kt[3][64 * 64];  // 24 KB
    __shared__ _Float16 Vt[2][64 * 64];  // 16 KB
    const int tid = threadIdx.x;
    const int lane = tid & 63, wv = tid >> 6;
    const int q31 = lane & 31, hi = lane >> 5;
    const int b = blockIdx.y >> 4, h = blockIdx.y & 15;
    const int q0w = blockIdx.x * 128 + wv * 32;
    const int kh = blockIdx.z;           // key half: 0 or 1
    const int kbase = kh << 10;
    const int nctx = n_ctx_p[0];

    // chunk-order rotation: co-resident blocks de-convoy their phases
    const int lin = blockIdx.x + (blockIdx.y << 4) + (blockIdx.z << 9);
    const int rot = ((lin >> 8) << 2) & 15;

    union fi { float f; int i; };
    fi ng; ng.f = -1e30f;
    const int NEGI = ng.i;

    // Q B-fragments: B[k=dim][n=q], lane n=q31, k = hi*8+j per kstep
    bf16x8 qf[4];
    {
        const ushort* qrow = qkb + (size_t)(b * N_ + q0w + q31) * 2048 + h * 64;
        #pragma unroll
        for (int ks = 0; ks < 4; ++ks)
            qf[ks] = *(const bf16x8*)(qrow + ks * 16 + hi * 8);
    }
    const size_t kgbase = (size_t)(b * N_ + kbase) * 2048 + 1024 + h * 64;
    const _Float16* vbase = vT + (size_t)((b * 16 + h) * 64) * 2048 + kbase;
    const unsigned* mrow = maskbits + (size_t)(q0w + q31) * 64 + (kbase >> 5);

    // per-thread staging offsets within one 64x64 chunk (2B elements):
    // slot r2: g = r2*256+tid, row = g>>3, col-group sg = (g&7)^(row&7)
    int goff[2], ldso[2];
    #pragma unroll
    for (int r2 = 0; r2 < 2; ++r2) {
        int g = r2 * 256 + tid, row = g >> 3, sg = (g & 7) ^ (row & 7);
        goff[r2] = row * 2048 + sg * 8;
        ldso[r2] = g * 8;
    }

    f32x16 O[2];
    O[0] = (f32x16)(0.f); O[1] = (f32x16)(0.f);
    float lrun = 0.f;

    // ---- prologue: FIFO = [mask0][K0 x2][V0 x2][K1 x2] (rotated chunks) ----
    const int cp0 = rot, cp1 = (rot + 1) & 15;
    uint2 mcur = *(const uint2*)&mrow[cp0 * 2];
    asm volatile("" ::: "memory");       // pin mask load before the asyncs
    {
        const ushort* gp0 = qkb + kgbase + (size_t)cp0 * (64 * 2048);
        #pragma unroll
        for (int r2 = 0; r2 < 2; ++r2) async16(gp0 + goff[r2], &Kt[0][ldso[r2]]);
        const _Float16* vp = vbase + cp0 * 64;
        #pragma unroll
        for (int r2 = 0; r2 < 2; ++r2) async16(vp + goff[r2], &Vt[0][ldso[r2]]);
        const ushort* gp1 = qkb + kgbase + (size_t)cp1 * (64 * 2048);
        #pragma unroll
        for (int r2 = 0; r2 < 2; ++r2) async16(gp1 + goff[r2], &Kt[1][ldso[r2]]);
    }

    const int swz = q31 & 7;
    int kb = 0;                           // Kt buffer holding chunk ci
    #pragma unroll 1
    for (int ci = 0; ci < 16; ++ci) {
        // bar1: all waves done computing chunk ci-1 -> buffers reusable
        asm volatile("s_barrier" ::: "memory");
        uint2 mnext = mcur;
        if (ci < 15) {
            const int cpv = (ci + 1 + rot) & 15;
            mnext = *(const uint2*)&mrow[cpv * 2];
            asm volatile("" ::: "memory");   // pin mask before V asyncs
            const _Float16* vp = vbase + cpv * 64;
            #pragma unroll
            for (int r2 = 0; r2 < 2; ++r2)
                async16(vp + goff[r2], &Vt[(ci + 1) & 1][ldso[r2]]);
        }
        if (ci < 14) {
            int nb = kb + 2; if (nb >= 3) nb -= 3;
            const int cpk = (ci + 2 + rot) & 15;
            const ushort* gp = qkb + kgbase + (size_t)cpk * (64 * 2048);
            #pragma unroll
            for (int r2 = 0; r2 < 2; ++r2)
                async16(gp + goff[r2], &Kt[nb][ldso[r2]]);
        }
        // counted wait: retire through V(ci)+mask(ci); keep newer prefetches
        // in flight. Steady: [Kci+1 x2][maskci+1][Vci+1 x2][Kci+2 x2] = 7.
        if (ci < 14)       asm volatile("s_waitcnt vmcnt(7)" ::: "memory");
        else if (ci == 14) asm volatile("s_waitcnt vmcnt(5)" ::: "memory");
        else               asm volatile("s_waitcnt vmcnt(0)" ::: "memory");
        // bar2: all waves' chunk-ci loads have landed
        asm volatile("s_barrier" ::: "memory");

        const ushort*   KT = Kt[kb];
        const _Float16* VT = Vt[ci & 1];
        const int cp = (ci + rot) & 15;
        const int c0g = kbase + cp * 64;
        const bool has_bias = (c0g < nctx);
        float lsum = 0.f;

        #pragma unroll
        for (int t = 0; t < 2; ++t) {
            // ---- S^T tile = K . Q^T ----
            f32x16 S = (f32x16)(0.f);
            const int rbase = (t * 32 + q31) * 64;
            __builtin_amdgcn_s_setprio(1);
            #pragma unroll
            for (int ks = 0; ks < 4; ++ks) {
                bf16x8 kf = *(const bf16x8*)&KT[rbase + (((ks * 2 + hi) ^ swz) << 3)];
                S = MFMA32B(kf, qf[ks], S);
            }
            __builtin_amdgcn_s_setprio(0);

            // ---- softmax (no max, no offset; mask via bfe+bfi) ----
            const unsigned msh = (t ? mcur.y : mcur.x) >> (hi * 4);
            unsigned pk[8];
            float lt = 0.f;
            #pragma unroll
            for (int g = 0; g < 4; ++g) {
                f32x4 bb;
                if (has_bias)
                    bb = *(const f32x4*)&biasrow[c0g + t * 32 + g * 8 + hi * 4];
                float pr[4];
                #pragma unroll
                for (int r = 0; r < 4; ++r) {
                    const int br = r + 8 * g;      // bit pos after >> 4*hi
                    float s = S[g * 4 + r];
                    if (has_bias) s += bb[r];
                    int mi = ((int)(msh << (31 - br))) >> 31;  // v_bfe_i32
                    fi su; su.f = s;
                    su.i = (mi & NEGI) | (su.i & ~mi);         // v_bfi_b32
                    pr[r] = __builtin_amdgcn_exp2f(su.f);
                }
                lt += (pr[0] + pr[1]) + (pr[2] + pr[3]);
                pk[g * 2 + 0] = pkrtz(pr[0], pr[1]);
                pk[g * 2 + 1] = pkrtz(pr[2], pr[3]);
            }
            lsum += lt;

            // ---- PV for this tile: out^T += V^T . P^T (k-slots 2t, 2t+1) ----
            __builtin_amdgcn_s_setprio(1);
            #pragma unroll
            for (int kss = 0; kss < 2; ++kss) {
                const int ks = 2 * t + kss, lo4 = kss * 4;
                unsigned w0 = pk[lo4 + 0], w1 = pk[lo4 + 1];
                unsigned w2 = pk[lo4 + 2], w3 = pk[lo4 + 3];
                plswap(w0, w2);
                plswap(w1, w3);
                union { f16x8 v; unsigned u[4]; } frag;
                frag.u[0] = w0; frag.u[1] = w1;
                frag.u[2] = w2; frag.u[3] = w3;
                #pragma unroll
                for (int t2 = 0; t2 < 2; ++t2) {
                    const int vb = (t2 * 32 + q31) * 64;
                    union { f16x8 v; int4 i4; } vf;
                    vf.i4 = *(const int4*)&VT[vb + (((ks * 2 + hi) ^ swz) << 3)];
                    O[t2] = MFMA32H(vf.v, frag.v, O[t2]);
                }
            }
            __builtin_amdgcn_s_setprio(0);
        }
        lrun += lsum;
        mcur = mnext;
        kb = kb + 1; if (kb >= 3) kb -= 3;
    }

    // ---- epilogue: normalize this half, store f16 partial + denominator ----
    float l = lrun + __shfl_xor(lrun, 32);
    float inv = 1.f / l;
    _Float16* orow = (kh ? op1 : op0)
                   + (size_t)(b * N_ + q0w + q31) * 1024 + h * 64;
    #pragma unroll
    for (int t = 0; t < 2; ++t)
        #pragma unroll
        for (int g = 0; g < 4; ++g) {
            ushort4 o;
            #pragma unroll
            for (int r = 0; r < 4; ++r) {
                _Float16 hv = (_Float16)(O[t][g * 4 + r] * inv);  // RTN cvt
                ((ushort*)&o)[r] = *(ushort*)&hv;
            }
            *(ushort4*)&orow[t * 32 + g * 8 + hi * 4] = o;
        }
    if (hi == 0)
        lpart[(kh << 16) + (b * 16 + h) * 2048 + q0w + q31] = l;
}

// ---------------------------------------------------------------------------
// Combine the two key-half partials: out = (o0*l0 + o1*l1) / (l0+l1), bf16.
// attb may alias op1: each thread reads exactly the bytes it overwrites.
// ---------------------------------------------------------------------------
__global__ __launch_bounds__(256) void combine(
    const _Float16* __restrict__ op0, const _Float16* __restrict__ op1,
    const float* __restrict__ lpart, ushort* __restrict__ attb)
{
    int t = blockIdx.x * 256 + threadIdx.x;
    size_t idx = (size_t)t * 4;
    int col = (int)(idx & 1023);          // h*64 + d
    int row = (int)(idx >> 10);           // b*2048 + q
    int h = col >> 6;
    int b = row >> 11, q = row & 2047;
    int lidx = (b * 16 + h) * 2048 + q;
    float l0 = lpart[lidx], l1 = lpart[65536 + lidx];
    float inv = 1.f / (l0 + l1);
    float w0 = l0 * inv, w1 = l1 * inv;
    f16x4 a0 = *(const f16x4*)(op0 + idx);
    f16x4 a1 = *(const f16x4*)(op1 + idx);
    ushort4 o;
    #pragma unroll
    for (int r = 0; r < 4; ++r)
        ((ushort*)&o)[r] = f2bf((float)a0[r] * w0 + (float)a1[r] * w1);
    *(ushort4*)(attb + idx) = o;
}

extern "C" void kernel_launch(void* const* d_in, const int* in_sizes, int n_in,
                              void* d_out, int out_size, void* d_ws, size_t ws_size,
                              hipStream_t stream)
{
    const float* x         = (const float*)d_in[0];
    const float* ctx_ppr   = (const float*)d_in[1];
    const float* ctx_trust = (const float*)d_in[2];
    const int*   n_ctx_p   = (const int*)d_in[3];
    const int*   attn_mask = (const int*)d_in[4];
    const float* W_in      = (const float*)d_in[5];
    const float* b_in      = (const float*)d_in[6];
    const float* W_out     = (const float*)d_in[7];
    const float* b_out     = (const float*)d_in[8];
    const float* log_alpha = (const float*)d_in[9];
    const float* trust_sc  = (const float*)d_in[10];
    float* out = (float*)d_out;

    char* ws = (char*)d_ws;
    ushort*    xb       = (ushort*)ws;    ws += (size_t)4096 * 1024 * 2;   // 8 MB
    ushort*    wib      = (ushort*)ws;    ws += (size_t)3072 * 1024 * 2;   // 6 MB
    ushort*    wob      = (ushort*)ws;    ws += (size_t)1024 * 1024 * 2;   // 2 MB
    ushort*    qkb      = (ushort*)ws;    ws += (size_t)4096 * 2048 * 2;   // 16 MB
    _Float16*  vT       = (_Float16*)ws;  ws += (size_t)2048 * 2048 * 2;   // 8 MB
    ushort*    attbuf   = (ushort*)ws;    ws += (size_t)4096 * 1024 * 2;   // 8 MB
    float*     biasrow  = (float*)ws;     ws += 2048 * 4;
    unsigned*  maskbits = (unsigned*)ws;  ws += (size_t)2048 * 64 * 4;     // 512 KB

    // Split-K partials live in workspace that is dead once the QKV GEMM ran:
    //   op0   aliases xb   (8 MB, exact fit)
    //   lpart aliases wib  (512 KB into 6 MB)
    //   op1   aliases attbuf (combine reads op1[i] then writes attb[i]:
    //                         byte-identical per thread, sequential stream)
    _Float16* op0   = (_Float16*)xb;
    _Float16* op1   = (_Float16*)attbuf;
    float*    lpart = (float*)wib;

    hipLaunchKernelGGL(preprocess, dim3(8712), dim3(256), 0, stream,
                       x, W_in, W_out, ctx_ppr, log_alpha, n_ctx_p, attn_mask,
                       xb, wib, wob, biasrow, maskbits);

    hipLaunchKernelGGL((gemm32<192, 1>), dim3(512), dim3(256), 0, stream,
                       xb, wib, b_in, (float*)nullptr, qkb, vT, TD_, 1024,
                       ctx_trust, trust_sc, n_ctx_p);

    hipLaunchKernelGGL(attn, dim3(16, 32, 2), dim3(256), 0, stream,
                       qkb, vT, maskbits, biasrow, n_ctx_p, op0, op1, lpart);

    hipLaunchKernelGGL(combine, dim3(4096), dim3(256), 0, stream,
                       op0, op1, lpart, attbuf);

    hipLaunchKernelGGL((gemm32<64, 0>), dim3(512), dim3(256), 0, stream,
                       attbuf, wob, b_out, out, (ushort*)nullptr, (_Float16*)nullptr,
                       1024, 1024, ctx_trust, trust_sc, n_ctx_p);
}